// Round 19
// baseline (185.115 us; speedup 1.0000x reference)
//
#include <hip/hip_runtime.h>
#include <hip/hip_bf16.h>
#include <stdint.h>

typedef __bf16 bf16;
typedef __attribute__((ext_vector_type(8))) __bf16 bf16x8;
typedef __attribute__((ext_vector_type(4))) float f32x4;
typedef __attribute__((ext_vector_type(8))) unsigned short u16x8;

#define LDS_U32 __attribute__((address_space(3))) uint32_t
#define GLB_U32 const __attribute__((address_space(1))) uint32_t
#define GLOAD16(g, l) __builtin_amdgcn_global_load_lds((GLB_U32*)(g), (LDS_U32*)(l), 16, 0, 0)

#define DSR(dst, addr, OFFLIT) \
  asm volatile("ds_read_b128 %0, %1 offset:" OFFLIT : "=v"(dst) : "v"(addr))

#define WAIT_LGKM0() asm volatile("s_waitcnt lgkmcnt(0)")
#define WAIT_LGKM4() asm volatile("s_waitcnt lgkmcnt(4)")
#define WAIT_VMN(n)  asm volatile("s_waitcnt vmcnt(" #n ")")
#define SB()         __builtin_amdgcn_sched_barrier(0)

// ---------------- fused f32 -> bf16 convert (all 5 inputs, one launch) ----------------
__global__ __launch_bounds__(256) void cvt_all(const float* __restrict__ q,
                                               const float* __restrict__ wq,
                                               const float* __restrict__ wk,
                                               const float* __restrict__ wv,
                                               const float* __restrict__ wo,
                                               bf16* __restrict__ qb,
                                               bf16* __restrict__ W3,
                                               bf16* __restrict__ wob) {
  const int b = blockIdx.x;
  const float* src;
  bf16* dst;
  int within;
  if (b < 2048) { src = q; dst = qb; within = b; }
  else {
    const int seg = (b - 2048) >> 8;      // 0..3
    within = (b - 2048) & 255;
    if (seg == 0)      { src = wq; dst = W3; }
    else if (seg == 1) { src = wk; dst = W3 + 1048576; }
    else if (seg == 2) { src = wv; dst = W3 + 2097152; }
    else               { src = wo; dst = wob; }
  }
  const int off = within * 1024;
#pragma unroll
  for (int it = 0; it < 4; ++it) {
    const int j = off + it * 256 + threadIdx.x;
    float4 v = reinterpret_cast<const float4*>(src)[j];
    ushort4 o;
    o.x = __builtin_bit_cast(unsigned short, (bf16)v.x);
    o.y = __builtin_bit_cast(unsigned short, (bf16)v.y);
    o.z = __builtin_bit_cast(unsigned short, (bf16)v.z);
    o.w = __builtin_bit_cast(unsigned short, (bf16)v.w);
    reinterpret_cast<ushort4*>(dst)[j] = o;
  }
}

// ============ 256 x (WN*64) double-buffered GEMM, C = alpha * A @ B^T ============
// r19 = r18 + 2D XCD CHUNK SWIZZLE. Evidence: every GEMM dispatch ~42us
// regardless of FLOPs/K/WN -> all bound by L3->L2 traffic (~250MB @ ~6TB/s).
// r17's 1D chunks gave each XCD full bx-rows: per by-row working set =
// A-panel + FULL B panel (4.5MB > 4MB L2) -> B thrashed, refetched per row.
// 2D chunk: XCD owns a CW x CH block sub-grid; CW B-panels (2MB) stay L2-
// resident while A streams -> QK L3 traffic ~144MB -> ~40MB.
// Mapping: f = by*gx+bx; xcd = f&7; i = f>>3; chunk grid cgx=gx/CW, cgy=gy/CH
// (cgx*cgy == 8); (cx,cy) = (xcd%cgx, xcd/cgx); bx = cx*CW + i%CW,
// by = cy*CH + i/CW. Bijective when gx%CW==0, gy%CH==0, cgx*cgy==8.
// K-loop (r16 counted-vmcnt, race-fixed) and epilogues unchanged from r18.
// EPI: 0 = bf16 C[z*sC+r*ldc+c]; 2 = f32 C[r*ldc+c];
//      4 = Vt via LDS-transpose (WN=2 only); 5 = QK route.
template <int EPI, int WN>
__global__ __launch_bounds__(512, 2) void g256(const bf16* __restrict__ A,
                                               const bf16* __restrict__ Bm,
                                               void* __restrict__ Cp,
                                               int K, float alpha,
                                               long sA, long sB, long sC, int ldc,
                                               int CW, int CH) {
  constexpr int BN = WN * 64;
  constexpr uint32_t PARB = 32768u + WN * 8192u;  // parity stride in bytes
  __shared__ bf16 smem_[PARB];                    // 2 parities x PARB bytes
  const long z = blockIdx.z;
  const int t = threadIdx.x;
  const int l = t & 63;
  const int w = t >> 6;
  const int wr = (w >> 2) * 128;        // wave row base within 256
  const int wc = (w & 3) * (WN * 16);   // wave col base within BN
  const int NT = K >> 6;

  // ---- 2D XCD chunk swizzle of the within-z flat block index ----
  int bx, by;
  {
    const int gx = (int)gridDim.x;
    const int gy = (int)gridDim.y;
    const int nxy = gx * gy;
    const int f = (int)blockIdx.y * gx + (int)blockIdx.x;
    const int cgx = (CW > 0) ? gx / CW : 0;
    if ((nxy & 7) == 0 && CW > 0 && CH > 0 && gx % CW == 0 && gy % CH == 0 &&
        cgx * (gy / CH) == 8) {
      const int xcd = f & 7;
      const int i = f >> 3;
      const int cx = xcd % cgx;
      const int cy = xcd / cgx;
      bx = cx * CW + (i % CW);
      by = cy * CH + (i / CW);
    } else if ((nxy & 7) == 0) {
      const int qq = nxy >> 3;
      const int wg = (f & 7) * qq + (f >> 3);
      bx = wg % gx;
      by = wg / gx;
    } else {
      bx = (int)blockIdx.x;
      by = (int)blockIdx.y;
    }
  }

  const bf16* Ab = A + z * sA + (long)(by * 256) * K;
  const bf16* Bb = Bm + z * sB + (long)(bx * BN) * K;

  // staging inverse map: thread t covers swizzled bytes [t*16, t*16+16) of one
  // 8KB 64-row unit; (r0,c0) = source row/col within the unit.
  uint32_t loc = (uint32_t)t * 16u;
  uint32_t g0 = loc ^ (((loc >> 9) & 1u) << 5);
  const int r0 = (int)(((g0 >> 10) >> 1) * 16 + ((g0 >> 6) & 15));  // 0..63
  const int c0 = (int)(((g0 >> 10) & 1) * 32 + ((g0 & 63) >> 1));   // 0..63

  // per-lane swizzled fragment read offset
  uint32_t lo_ = (uint32_t)((l & 15) * 64 + (l >> 4) * 16);
  const uint32_t lane_off = lo_ ^ (((lo_ >> 9) & 1u) << 5);
  const uint32_t aRegion = (uint32_t)(wr >> 7) * 16384u;
  const uint32_t smem_base = (uint32_t)(size_t)&smem_[0];
  const uint32_t aBase = smem_base + aRegion + lane_off;  // + parity + quad*4096

  // per-n B fragment base addresses (row = wc + n*16 within B panel)
  uint32_t bA[WN];
#pragma unroll
  for (int n = 0; n < WN; ++n) {
    const uint32_t row = (uint32_t)(wc + n * 16);
    bA[n] = smem_base + 32768u + (row >> 6) * 8192u + ((row & 63u) >> 4) * 2048u + lane_off;
  }

  // stage one 64-row unit of tile `tile` into parity (tile&1)
  auto STAGE1 = [&](const bf16* mat, int unit, int tile, uint32_t isB) {
    uint32_t dst = (uint32_t)(tile & 1) * PARB + isB + (uint32_t)unit * 8192u + (uint32_t)t * 16u;
    const bf16* src = mat + (long)(unit * 64 + r0) * K + tile * 64 + c0;
    GLOAD16(src, smem_ + (dst >> 1));
  };

  f32x4 acc[8][WN] = {};

  // ---- prologue: A(0) + B(0) into parity 0 (one-time full drain)
  STAGE1(Ab, 0, 0, 0u); STAGE1(Ab, 1, 0, 0u); STAGE1(Ab, 2, 0, 0u); STAGE1(Ab, 3, 0, 0u);
#pragma unroll
  for (int u = 0; u < WN; ++u) STAGE1(Bb, u, 0, 32768u);
  SB();
  WAIT_VMN(0);
  __builtin_amdgcn_s_barrier();

  // MFMA for output quad Q (acc rows Q*2, Q*2+1) using aF slot S
#define MFMAQ(Q, S)                                                                  \
  _Pragma("unroll") for (int mi = 0; mi < 2; ++mi)                                   \
  _Pragma("unroll") for (int n = 0; n < WN; ++n)                                     \
  _Pragma("unroll") for (int kk = 0; kk < 2; ++kk)                                   \
    acc[(Q) * 2 + mi][n] = __builtin_amdgcn_mfma_f32_16x16x32_bf16(                  \
        __builtin_bit_cast(bf16x8, aF[S][mi][kk]), __builtin_bit_cast(bf16x8, bF[n][kk]), \
        acc[(Q) * 2 + mi][n], 0, 0, 0);

  for (int T = 0; T < NT; ++T) {
    const uint32_t pb = (uint32_t)(T & 1) * PARB;
    const uint32_t aA = aBase + pb;
    f32x4 bF[WN][2];
    f32x4 aF[2][2][2];  // [slot][mi][kk]

    // ---- top: issue B(T+1) + A units {0,2} (phase-A readers' units) ----
    if (T + 1 < NT) {
#pragma unroll
      for (int u = 0; u < WN; ++u) STAGE1(Bb, u, T + 1, 32768u);
      STAGE1(Ab, 0, T + 1, 0u); STAGE1(Ab, 2, T + 1, 0u);
    }

    // ---- phase A: issue bF(2WN) + aF q0(4) + q1(4); data landed last tile ----
#pragma unroll
    for (int n = 0; n < WN; ++n) {
      DSR(bF[n][0], bA[n] + pb, "0");
      DSR(bF[n][1], bA[n] + pb, "1024");
    }
    DSR(aF[0][0][0], aA, "0");    DSR(aF[0][0][1], aA, "1024");
    DSR(aF[0][1][0], aA, "2048"); DSR(aF[0][1][1], aA, "3072");
    DSR(aF[1][0][0], aA, "4096"); DSR(aF[1][0][1], aA, "5120");
    DSR(aF[1][1][0], aA, "6144"); DSR(aF[1][1][1], aA, "7168");
    WAIT_LGKM4();   // bF + q0 landed; q1 (4 reads) in flight
    SB();           // rule #18: keep MFMA below the wait
    __builtin_amdgcn_s_setprio(1);
    MFMAQ(0, 0)
    __builtin_amdgcn_s_setprio(0);
    WAIT_LGKM0();   // q1 landed
    SB();
    __builtin_amdgcn_s_setprio(1);
    MFMAQ(1, 1)
    __builtin_amdgcn_s_setprio(0);

    // ---- mid: issue A units {1,3} of T+1 (phase-B readers' units) ----
    if (T + 1 < NT) { STAGE1(Ab, 1, T + 1, 0u); STAGE1(Ab, 3, T + 1, 0u); }

    // ---- mid wait: A1,A3(T) landed (issued mid of T-1; 1-tile cover).
    SB();
    if (T + 1 < NT) {
      if constexpr (WN == 2) { WAIT_VMN(6); } else { WAIT_VMN(8); }
    } else {
      WAIT_VMN(0);
    }
    __builtin_amdgcn_s_barrier();

    // ---- phase B: issue aF q2(4) + q3(4), reuse slots ----
    DSR(aF[0][0][0], aA, "8192");  DSR(aF[0][0][1], aA, "9216");
    DSR(aF[0][1][0], aA, "10240"); DSR(aF[0][1][1], aA, "11264");
    DSR(aF[1][0][0], aA, "12288"); DSR(aF[1][0][1], aA, "13312");
    DSR(aF[1][1][0], aA, "14336"); DSR(aF[1][1][1], aA, "15360");
    WAIT_LGKM4();   // q2 landed; q3 in flight
    SB();
    __builtin_amdgcn_s_setprio(1);
    MFMAQ(2, 0)
    __builtin_amdgcn_s_setprio(0);
    WAIT_LGKM0();   // q3 landed
    SB();
    __builtin_amdgcn_s_setprio(1);
    MFMAQ(3, 1)
    __builtin_amdgcn_s_setprio(0);

    // ---- boundary: B,A0,A2(T+1) landed; A1,A3(T+1) STAY IN FLIGHT ----
    SB();
    if (T + 1 < NT) { WAIT_VMN(2); } else { WAIT_VMN(0); }
    __builtin_amdgcn_s_barrier();
  }
#undef MFMAQ

  if constexpr (EPI == 4) {
    // ---- V-proj epilogue: transpose 256s x 128e block output through LDS,
    // then coalesced Vt stores (r18, verified).
    constexpr int STR = 264;  // elems per e-row
#pragma unroll
    for (int m = 0; m < 8; ++m)
#pragma unroll
      for (int n = 0; n < WN; ++n) {
        const int e = wc + n * 16 + (l & 15);
        const int s = wr + (l >> 4) * 4 + m * 16;
        ushort4 pk;
        pk.x = __builtin_bit_cast(unsigned short, (bf16)(acc[m][n][0] * alpha));
        pk.y = __builtin_bit_cast(unsigned short, (bf16)(acc[m][n][1] * alpha));
        pk.z = __builtin_bit_cast(unsigned short, (bf16)(acc[m][n][2] * alpha));
        pk.w = __builtin_bit_cast(unsigned short, (bf16)(acc[m][n][3] * alpha));
        *reinterpret_cast<ushort4*>(&smem_[e * STR + s]) = pk;  // 8B, aligned
      }
    __syncthreads();
    bf16* Vt = (bf16*)Cp;
    const int bq = by >> 3;             // batch (by*256 / 2048)
    const int sbase = (by & 7) * 256;   // s offset within batch
    const int e0 = t >> 2;              // 0..127
#pragma unroll
    for (int it = 0; it < 8; ++it) {
      const int c = (t & 3) + it * 4;   // chunk index 0..31
      uint4 v = *reinterpret_cast<const uint4*>(&smem_[e0 * STR + c * 8]);
      *reinterpret_cast<uint4*>(
          &Vt[(long)bq * 2097152 + (long)(bx * BN + e0) * 2048 + sbase + c * 8]) = v;
    }
    return;
  }

  // ---- generic epilogue: C/D layout col = lane&15, row = (lane>>4)*4 + i
  const int orow0 = by * 256 + wr + (l >> 4) * 4;
  const int ocol0 = bx * BN + wc + (l & 15);
#pragma unroll
  for (int m = 0; m < 8; ++m)
#pragma unroll
    for (int n = 0; n < WN; ++n)
#pragma unroll
      for (int i = 0; i < 4; ++i) {
        const long r = orow0 + m * 16 + i;
        const long c = ocol0 + n * 16;
        const float v = acc[m][n][i] * alpha;
        if constexpr (EPI == 0) {
          ((bf16*)Cp)[z * sC + r * ldc + c] = (bf16)v;
        } else if constexpr (EPI == 2) {
          ((float*)Cp)[r * ldc + c] = v;
        } else if constexpr (EPI == 5) {
          // QK-proj route: c<1024 -> Q, else K  (rows r = b*2048+s)
          bf16* Qb = (bf16*)Cp;
          bf16* Kb = Qb + 8388608;  // 8192*1024
          if (c < 1024) Qb[r * 1024 + c] = (bf16)v;
          else Kb[r * 1024 + (c - 1024)] = (bf16)v;
        }
      }
}

// ---------------- row softmax, in place, rows of 2048 bf16 ----------------
__global__ __launch_bounds__(256) void softmax_rows(bf16* __restrict__ P) {
  const long row = blockIdx.x;
  bf16* p = P + row * 2048;
  const int t = threadIdx.x;
  const int lane = t & 63;
  const int wave = t >> 6;

  u16x8 raw = *reinterpret_cast<const u16x8*>(p + t * 8);
  float v[8];
#pragma unroll
  for (int j = 0; j < 8; ++j) {
    uint32_t bits = ((uint32_t)raw[j]) << 16;
    v[j] = __builtin_bit_cast(float, bits);
  }
  float m = v[0];
#pragma unroll
  for (int j = 1; j < 8; ++j) m = fmaxf(m, v[j]);
#pragma unroll
  for (int off = 32; off > 0; off >>= 1) m = fmaxf(m, __shfl_xor(m, off, 64));
  __shared__ float redm[4];
  __shared__ float reds[4];
  if (lane == 0) redm[wave] = m;
  __syncthreads();
  m = fmaxf(fmaxf(redm[0], redm[1]), fmaxf(redm[2], redm[3]));

  float s = 0.f;
#pragma unroll
  for (int j = 0; j < 8; ++j) {
    v[j] = __expf(v[j] - m);
    s += v[j];
  }
#pragma unroll
  for (int off = 32; off > 0; off >>= 1) s += __shfl_xor(s, off, 64);
  if (lane == 0) reds[wave] = s;
  __syncthreads();
  s = reds[0] + reds[1] + reds[2] + reds[3];
  const float inv = 1.f / s;

  u16x8 o;
#pragma unroll
  for (int j = 0; j < 8; ++j) o[j] = __builtin_bit_cast(unsigned short, (bf16)(v[j] * inv));
  *reinterpret_cast<u16x8*>(p + t * 8) = o;
}

// ---------------- launch ----------------
extern "C" void kernel_launch(void* const* d_in, const int* in_sizes, int n_in,
                              void* d_out, int out_size, void* d_ws, size_t ws_size,
                              hipStream_t stream) {
  const float* q = (const float*)d_in[0];
  const float* wq = (const float*)d_in[1];
  const float* wk = (const float*)d_in[2];
  const float* wv = (const float*)d_in[3];
  const float* wo = (const float*)d_in[4];
  float* out = (float*)d_out;

  constexpr int B = 4, S = 2048, D = 1024;
  constexpr long SD = (long)S * D;  // 2,097,152
  constexpr long SS = (long)S * S;  // 4,194,304
  constexpr long DD = (long)D * D;  // 1,048,576

  bf16* wsb = (bf16*)d_ws;
  bf16* qb = wsb;             // B*SD
  bf16* W3 = qb + B * SD;     // 3*DD  (wq;wk;wv stacked rows)
  bf16* wob = W3 + 3 * DD;    // DD
  bf16* Qb = wob + DD;        // B*SD
  bf16* Kb = Qb + B * SD;     // B*SD
  bf16* Vt = Kb + B * SD;     // B*SD, layout [B][D][S]
  bf16* P = Vt + B * SD;      // B*SS
  bf16* X = P + B * SS;       // B*SD, layout [B][D][S] == bugged buffer

  cvt_all<<<3072, 256, 0, stream>>>(q, wq, wk, wv, wo, qb, W3, wob);

  // QK-proj: grid 8x32; 2D chunks 4bx x 8by (chunk-grid 2x4 = 8 XCDs):
  // per-XCD working set = 4 B-panels (2MB) resident + A streaming.
  g256<5, 4><<<dim3(8, 32, 1), 512, 0, stream>>>(qb, W3, Qb, D, 1.f, 0, 0, 0, 0, 4, 8);
  // V-proj: grid 8x32, chunks 4x8.
  g256<4, 2><<<dim3(8, 32, 1), 512, 0, stream>>>(qb, W3 + 2 * DD, Vt, D, 1.f, 0, 0, 0, 0, 4, 8);
  // scores: per-z grid 8x8, chunks 4bx x 2by (chunk-grid 2x4).
  g256<0, 4><<<dim3(8, 8, B), 512, 0, stream>>>(Qb, Kb, P, D, 0.125f, SD, SD, SS, S, 4, 2);
  softmax_rows<<<B * S, 256, 0, stream>>>(P);
  // PV as Xt = Vt @ P^T: per-z grid 16x4, chunks 4bx x 2by (chunk-grid 4x2).
  g256<0, 2><<<dim3(16, 4, B), 512, 0, stream>>>(Vt, P, X, S, 1.f, SD, SS, SD, S, 4, 2);
  // out-proj: grid 8x32, chunks 4x8.
  g256<2, 2><<<dim3(8, 32, 1), 512, 0, stream>>>(X, wob, out, D, 1.f, 0, 0, 0, D, 4, 8);
}

// Round 20
// 181.218 us; speedup vs baseline: 1.0215x; 1.0215x over previous
//
#include <hip/hip_runtime.h>
#include <hip/hip_bf16.h>
#include <stdint.h>

typedef __bf16 bf16;
typedef __attribute__((ext_vector_type(8))) __bf16 bf16x8;
typedef __attribute__((ext_vector_type(4))) float f32x4;
typedef __attribute__((ext_vector_type(8))) unsigned short u16x8;

#define LDS_U32 __attribute__((address_space(3))) uint32_t
#define GLB_U32 const __attribute__((address_space(1))) uint32_t
#define GLOAD16(g, l) __builtin_amdgcn_global_load_lds((GLB_U32*)(g), (LDS_U32*)(l), 16, 0, 0)

#define DSR(dst, addr, OFFLIT) \
  asm volatile("ds_read_b128 %0, %1 offset:" OFFLIT : "=v"(dst) : "v"(addr))

#define WAIT_LGKM0() asm volatile("s_waitcnt lgkmcnt(0)")
#define WAIT_LGKM4() asm volatile("s_waitcnt lgkmcnt(4)")
#define WAIT_VMN(n)  asm volatile("s_waitcnt vmcnt(" #n ")")
#define SB()         __builtin_amdgcn_sched_barrier(0)

// ---------------- fused f32 -> bf16 convert (all 5 inputs, one launch) ----------------
__global__ __launch_bounds__(256) void cvt_all(const float* __restrict__ q,
                                               const float* __restrict__ wq,
                                               const float* __restrict__ wk,
                                               const float* __restrict__ wv,
                                               const float* __restrict__ wo,
                                               bf16* __restrict__ qb,
                                               bf16* __restrict__ W3,
                                               bf16* __restrict__ wob) {
  const int b = blockIdx.x;
  const float* src;
  bf16* dst;
  int within;
  if (b < 2048) { src = q; dst = qb; within = b; }
  else {
    const int seg = (b - 2048) >> 8;      // 0..3
    within = (b - 2048) & 255;
    if (seg == 0)      { src = wq; dst = W3; }
    else if (seg == 1) { src = wk; dst = W3 + 1048576; }
    else if (seg == 2) { src = wv; dst = W3 + 2097152; }
    else               { src = wo; dst = wob; }
  }
  const int off = within * 1024;
#pragma unroll
  for (int it = 0; it < 4; ++it) {
    const int j = off + it * 256 + threadIdx.x;
    float4 v = reinterpret_cast<const float4*>(src)[j];
    ushort4 o;
    o.x = __builtin_bit_cast(unsigned short, (bf16)v.x);
    o.y = __builtin_bit_cast(unsigned short, (bf16)v.y);
    o.z = __builtin_bit_cast(unsigned short, (bf16)v.z);
    o.w = __builtin_bit_cast(unsigned short, (bf16)v.w);
    reinterpret_cast<ushort4*>(dst)[j] = o;
  }
}

// ============ 256 x (WN*64) double-buffered GEMM, C = alpha * A @ B^T ============
// r20 = r19 + EPI=6: QK and V-proj FUSED in one dispatch. r19 showed V-proj
// at 409 TF with 82MB fetch (ideal 18MB, 4.5x over-fetch of the SAME qb rows
// QK reads at 818 TF-rate). Fusing makes phase-2's A panels L2-hot and kills
// one dispatch: phase 1 = QK K-loop (WN=4, r16 counted-vmcnt schedule) +
// EPI=5 epilogue; phase 2 = V K-loop over the same A rows (B = wv 128-row
// panel, 2 LDS units, WN=2-shaped MFMA into reused acc[.][0..1], simple
// r12-style dbuf sync) + r18 LDS-transpose Vt epilogue.
// K-loop and other epilogues unchanged from r19 (2D XCD chunks kept).
template <int EPI, int WN>
__global__ __launch_bounds__(512, 2) void g256(const bf16* __restrict__ A,
                                               const bf16* __restrict__ Bm,
                                               void* __restrict__ Cp,
                                               int K, float alpha,
                                               long sA, long sB, long sC, int ldc,
                                               int CW, int CH) {
  constexpr int BN = WN * 64;
  constexpr uint32_t PARB = 32768u + WN * 8192u;  // parity stride in bytes
  __shared__ bf16 smem_[PARB];                    // 2 parities x PARB bytes
  const long z = blockIdx.z;
  const int t = threadIdx.x;
  const int l = t & 63;
  const int w = t >> 6;
  const int wr = (w >> 2) * 128;        // wave row base within 256
  const int wc = (w & 3) * (WN * 16);   // wave col base within BN
  const int NT = K >> 6;

  // ---- 2D XCD chunk swizzle of the within-z flat block index ----
  int bx, by;
  {
    const int gx = (int)gridDim.x;
    const int gy = (int)gridDim.y;
    const int nxy = gx * gy;
    const int f = (int)blockIdx.y * gx + (int)blockIdx.x;
    const int cgx = (CW > 0) ? gx / CW : 0;
    if ((nxy & 7) == 0 && CW > 0 && CH > 0 && gx % CW == 0 && gy % CH == 0 &&
        cgx * (gy / CH) == 8) {
      const int xcd = f & 7;
      const int i = f >> 3;
      const int cx = xcd % cgx;
      const int cy = xcd / cgx;
      bx = cx * CW + (i % CW);
      by = cy * CH + (i / CW);
    } else if ((nxy & 7) == 0) {
      const int qq = nxy >> 3;
      const int wg = (f & 7) * qq + (f >> 3);
      bx = wg % gx;
      by = wg / gx;
    } else {
      bx = (int)blockIdx.x;
      by = (int)blockIdx.y;
    }
  }

  const bf16* Ab = A + z * sA + (long)(by * 256) * K;
  const bf16* Bb = Bm + z * sB + (long)(bx * BN) * K;

  // staging inverse map: thread t covers swizzled bytes [t*16, t*16+16) of one
  // 8KB 64-row unit; (r0,c0) = source row/col within the unit.
  uint32_t loc = (uint32_t)t * 16u;
  uint32_t g0 = loc ^ (((loc >> 9) & 1u) << 5);
  const int r0 = (int)(((g0 >> 10) >> 1) * 16 + ((g0 >> 6) & 15));  // 0..63
  const int c0 = (int)(((g0 >> 10) & 1) * 32 + ((g0 & 63) >> 1));   // 0..63

  // per-lane swizzled fragment read offset
  uint32_t lo_ = (uint32_t)((l & 15) * 64 + (l >> 4) * 16);
  const uint32_t lane_off = lo_ ^ (((lo_ >> 9) & 1u) << 5);
  const uint32_t aRegion = (uint32_t)(wr >> 7) * 16384u;
  const uint32_t smem_base = (uint32_t)(size_t)&smem_[0];
  const uint32_t aBase = smem_base + aRegion + lane_off;  // + parity + quad*4096

  // per-n B fragment base addresses (row = wc + n*16 within B panel)
  uint32_t bA[WN];
#pragma unroll
  for (int n = 0; n < WN; ++n) {
    const uint32_t row = (uint32_t)(wc + n * 16);
    bA[n] = smem_base + 32768u + (row >> 6) * 8192u + ((row & 63u) >> 4) * 2048u + lane_off;
  }

  // stage one 64-row unit of tile `tile` into parity (tile&1)
  auto STAGE1 = [&](const bf16* mat, int unit, int tile, uint32_t isB) {
    uint32_t dst = (uint32_t)(tile & 1) * PARB + isB + (uint32_t)unit * 8192u + (uint32_t)t * 16u;
    const bf16* src = mat + (long)(unit * 64 + r0) * K + tile * 64 + c0;
    GLOAD16(src, smem_ + (dst >> 1));
  };

  f32x4 acc[8][WN] = {};

  // ---- prologue: A(0) + B(0) into parity 0 (one-time full drain)
  STAGE1(Ab, 0, 0, 0u); STAGE1(Ab, 1, 0, 0u); STAGE1(Ab, 2, 0, 0u); STAGE1(Ab, 3, 0, 0u);
#pragma unroll
  for (int u = 0; u < WN; ++u) STAGE1(Bb, u, 0, 32768u);
  SB();
  WAIT_VMN(0);
  __builtin_amdgcn_s_barrier();

  // MFMA for output quad Q (acc rows Q*2, Q*2+1) using aF slot S
#define MFMAQ(Q, S)                                                                  \
  _Pragma("unroll") for (int mi = 0; mi < 2; ++mi)                                   \
  _Pragma("unroll") for (int n = 0; n < WN; ++n)                                     \
  _Pragma("unroll") for (int kk = 0; kk < 2; ++kk)                                   \
    acc[(Q) * 2 + mi][n] = __builtin_amdgcn_mfma_f32_16x16x32_bf16(                  \
        __builtin_bit_cast(bf16x8, aF[S][mi][kk]), __builtin_bit_cast(bf16x8, bF[n][kk]), \
        acc[(Q) * 2 + mi][n], 0, 0, 0);

  for (int T = 0; T < NT; ++T) {
    const uint32_t pb = (uint32_t)(T & 1) * PARB;
    const uint32_t aA = aBase + pb;
    f32x4 bF[WN][2];
    f32x4 aF[2][2][2];  // [slot][mi][kk]

    // ---- top: issue B(T+1) + A units {0,2} (phase-A readers' units) ----
    if (T + 1 < NT) {
#pragma unroll
      for (int u = 0; u < WN; ++u) STAGE1(Bb, u, T + 1, 32768u);
      STAGE1(Ab, 0, T + 1, 0u); STAGE1(Ab, 2, T + 1, 0u);
    }

    // ---- phase A: issue bF(2WN) + aF q0(4) + q1(4) ----
#pragma unroll
    for (int n = 0; n < WN; ++n) {
      DSR(bF[n][0], bA[n] + pb, "0");
      DSR(bF[n][1], bA[n] + pb, "1024");
    }
    DSR(aF[0][0][0], aA, "0");    DSR(aF[0][0][1], aA, "1024");
    DSR(aF[0][1][0], aA, "2048"); DSR(aF[0][1][1], aA, "3072");
    DSR(aF[1][0][0], aA, "4096"); DSR(aF[1][0][1], aA, "5120");
    DSR(aF[1][1][0], aA, "6144"); DSR(aF[1][1][1], aA, "7168");
    WAIT_LGKM4();   // bF + q0 landed; q1 in flight
    SB();           // rule #18
    __builtin_amdgcn_s_setprio(1);
    MFMAQ(0, 0)
    __builtin_amdgcn_s_setprio(0);
    WAIT_LGKM0();
    SB();
    __builtin_amdgcn_s_setprio(1);
    MFMAQ(1, 1)
    __builtin_amdgcn_s_setprio(0);

    // ---- mid: issue A units {1,3} of T+1 ----
    if (T + 1 < NT) { STAGE1(Ab, 1, T + 1, 0u); STAGE1(Ab, 3, T + 1, 0u); }

    // ---- mid wait: A1,A3(T) landed (issued mid of T-1)
    SB();
    if (T + 1 < NT) {
      if constexpr (WN == 2) { WAIT_VMN(6); } else { WAIT_VMN(8); }
    } else {
      WAIT_VMN(0);
    }
    __builtin_amdgcn_s_barrier();

    // ---- phase B: aF q2 + q3 ----
    DSR(aF[0][0][0], aA, "8192");  DSR(aF[0][0][1], aA, "9216");
    DSR(aF[0][1][0], aA, "10240"); DSR(aF[0][1][1], aA, "11264");
    DSR(aF[1][0][0], aA, "12288"); DSR(aF[1][0][1], aA, "13312");
    DSR(aF[1][1][0], aA, "14336"); DSR(aF[1][1][1], aA, "15360");
    WAIT_LGKM4();
    SB();
    __builtin_amdgcn_s_setprio(1);
    MFMAQ(2, 0)
    __builtin_amdgcn_s_setprio(0);
    WAIT_LGKM0();
    SB();
    __builtin_amdgcn_s_setprio(1);
    MFMAQ(3, 1)
    __builtin_amdgcn_s_setprio(0);

    // ---- boundary: B,A0,A2(T+1) landed; A1,A3(T+1) stay in flight ----
    SB();
    if (T + 1 < NT) { WAIT_VMN(2); } else { WAIT_VMN(0); }
    __builtin_amdgcn_s_barrier();
  }
#undef MFMAQ

  if constexpr (EPI == 4) {
    // ---- V-proj epilogue: LDS transpose + coalesced Vt stores (r18) ----
    constexpr int STR = 264;
#pragma unroll
    for (int m = 0; m < 8; ++m)
#pragma unroll
      for (int n = 0; n < WN; ++n) {
        const int e = wc + n * 16 + (l & 15);
        const int s = wr + (l >> 4) * 4 + m * 16;
        ushort4 pk;
        pk.x = __builtin_bit_cast(unsigned short, (bf16)(acc[m][n][0] * alpha));
        pk.y = __builtin_bit_cast(unsigned short, (bf16)(acc[m][n][1] * alpha));
        pk.z = __builtin_bit_cast(unsigned short, (bf16)(acc[m][n][2] * alpha));
        pk.w = __builtin_bit_cast(unsigned short, (bf16)(acc[m][n][3] * alpha));
        *reinterpret_cast<ushort4*>(&smem_[e * STR + s]) = pk;
      }
    __syncthreads();
    bf16* Vt = (bf16*)Cp;
    const int bq = by >> 3;
    const int sbase = (by & 7) * 256;
    const int e0 = t >> 2;
#pragma unroll
    for (int it = 0; it < 8; ++it) {
      const int c = (t & 3) + it * 4;
      uint4 v = *reinterpret_cast<const uint4*>(&smem_[e0 * STR + c * 8]);
      *reinterpret_cast<uint4*>(
          &Vt[(long)bq * 2097152 + (long)(bx * BN + e0) * 2048 + sbase + c * 8]) = v;
    }
    return;
  }

  if constexpr (EPI == 6) {
    // ======== fused QKV: QK epilogue, then V phase over L2-hot A rows ========
    {
      const int orow0 = by * 256 + wr + (l >> 4) * 4;
      const int ocol0 = bx * 256 + wc + (l & 15);
      bf16* Qb = (bf16*)Cp;
      bf16* Kb = Qb + 8388608;
#pragma unroll
      for (int m = 0; m < 8; ++m)
#pragma unroll
        for (int n = 0; n < WN; ++n)
#pragma unroll
          for (int i = 0; i < 4; ++i) {
            const long r = orow0 + m * 16 + i;
            const long c = ocol0 + n * 16;
            const float v = acc[m][n][i];
            if (c < 1024) Qb[r * 1024 + c] = (bf16)v;
            else Kb[r * 1024 + (c - 1024)] = (bf16)v;
          }
    }
    // V phase: B = wv panel rows [bx*128, bx*128+128), 2 LDS units.
    const bf16* Bv = Bm + 2 * 1048576 + (long)(bx * 128) * K;
    uint32_t bA2[2];
#pragma unroll
    for (int n = 0; n < 2; ++n) {
      const uint32_t row = (uint32_t)((w & 3) * 32 + n * 16);  // 0..127
      bA2[n] = smem_base + 32768u + (row >> 6) * 8192u + ((row & 63u) >> 4) * 2048u + lane_off;
    }
#pragma unroll
    for (int m = 0; m < 8; ++m)
#pragma unroll
      for (int n = 0; n < 2; ++n) acc[m][n] = f32x4{0.f, 0.f, 0.f, 0.f};

    __builtin_amdgcn_s_barrier();  // QK epilogue writes done; LDS reusable
    STAGE1(Ab, 0, 0, 0u); STAGE1(Ab, 1, 0, 0u); STAGE1(Ab, 2, 0, 0u); STAGE1(Ab, 3, 0, 0u);
    STAGE1(Bv, 0, 0, 32768u); STAGE1(Bv, 1, 0, 32768u);
    SB();
    WAIT_VMN(0);
    __builtin_amdgcn_s_barrier();

#define MFMAQ2(Q, S)                                                                 \
    _Pragma("unroll") for (int mi = 0; mi < 2; ++mi)                                 \
    _Pragma("unroll") for (int n = 0; n < 2; ++n)                                    \
    _Pragma("unroll") for (int kk = 0; kk < 2; ++kk)                                 \
      acc[(Q) * 2 + mi][n] = __builtin_amdgcn_mfma_f32_16x16x32_bf16(                \
          __builtin_bit_cast(bf16x8, aF[S][mi][kk]), __builtin_bit_cast(bf16x8, bF2[n][kk]), \
          acc[(Q) * 2 + mi][n], 0, 0, 0);

    for (int T = 0; T < NT; ++T) {
      const uint32_t pb = (uint32_t)(T & 1) * PARB;
      const uint32_t aA = aBase + pb;
      f32x4 bF2[2][2];
      f32x4 aF[2][2][2];
      // frontload T+1 into other parity (WAR-free)
      if (T + 1 < NT) {
        STAGE1(Ab, 0, T + 1, 0u); STAGE1(Ab, 1, T + 1, 0u);
        STAGE1(Ab, 2, T + 1, 0u); STAGE1(Ab, 3, T + 1, 0u);
        STAGE1(Bv, 0, T + 1, 32768u); STAGE1(Bv, 1, T + 1, 32768u);
      }
      // phase A: bF2 (4) + aF q0,q1 (8)
      DSR(bF2[0][0], bA2[0] + pb, "0"); DSR(bF2[0][1], bA2[0] + pb, "1024");
      DSR(bF2[1][0], bA2[1] + pb, "0"); DSR(bF2[1][1], bA2[1] + pb, "1024");
      DSR(aF[0][0][0], aA, "0");    DSR(aF[0][0][1], aA, "1024");
      DSR(aF[0][1][0], aA, "2048"); DSR(aF[0][1][1], aA, "3072");
      DSR(aF[1][0][0], aA, "4096"); DSR(aF[1][0][1], aA, "5120");
      DSR(aF[1][1][0], aA, "6144"); DSR(aF[1][1][1], aA, "7168");
      WAIT_LGKM4();
      SB();
      __builtin_amdgcn_s_setprio(1);
      MFMAQ2(0, 0)
      __builtin_amdgcn_s_setprio(0);
      WAIT_LGKM0();
      SB();
      __builtin_amdgcn_s_setprio(1);
      MFMAQ2(1, 1)
      __builtin_amdgcn_s_setprio(0);
      // phase B: aF q2,q3
      DSR(aF[0][0][0], aA, "8192");  DSR(aF[0][0][1], aA, "9216");
      DSR(aF[0][1][0], aA, "10240"); DSR(aF[0][1][1], aA, "11264");
      DSR(aF[1][0][0], aA, "12288"); DSR(aF[1][0][1], aA, "13312");
      DSR(aF[1][1][0], aA, "14336"); DSR(aF[1][1][1], aA, "15360");
      WAIT_LGKM4();
      SB();
      __builtin_amdgcn_s_setprio(1);
      MFMAQ2(2, 0)
      __builtin_amdgcn_s_setprio(0);
      WAIT_LGKM0();
      SB();
      __builtin_amdgcn_s_setprio(1);
      MFMAQ2(3, 1)
      __builtin_amdgcn_s_setprio(0);
      // boundary
      SB();
      if (T + 1 < NT) { WAIT_VMN(0); } else { WAIT_VMN(0); }
      __builtin_amdgcn_s_barrier();
    }
#undef MFMAQ2

    // V epilogue: LDS transpose (cols bx*128 + e), coalesced Vt stores
    {
      constexpr int STR = 264;
#pragma unroll
      for (int m = 0; m < 8; ++m)
#pragma unroll
        for (int n = 0; n < 2; ++n) {
          const int e = (w & 3) * 32 + n * 16 + (l & 15);
          const int s = wr + (l >> 4) * 4 + m * 16;
          ushort4 pk;
          pk.x = __builtin_bit_cast(unsigned short, (bf16)acc[m][n][0]);
          pk.y = __builtin_bit_cast(unsigned short, (bf16)acc[m][n][1]);
          pk.z = __builtin_bit_cast(unsigned short, (bf16)acc[m][n][2]);
          pk.w = __builtin_bit_cast(unsigned short, (bf16)acc[m][n][3]);
          *reinterpret_cast<ushort4*>(&smem_[e * STR + s]) = pk;
        }
      __syncthreads();
      bf16* Vt = (bf16*)Cp + 2 * 8388608;  // Qb + 2*8192*1024
      const int bq = by >> 3;
      const int sbase = (by & 7) * 256;
      const int e0 = t >> 2;  // 0..127
#pragma unroll
      for (int it = 0; it < 8; ++it) {
        const int c = (t & 3) + it * 4;
        uint4 v = *reinterpret_cast<const uint4*>(&smem_[e0 * STR + c * 8]);
        *reinterpret_cast<uint4*>(
            &Vt[(long)bq * 2097152 + (long)(bx * 128 + e0) * 2048 + sbase + c * 8]) = v;
      }
    }
    return;
  }

  // ---- generic epilogue: C/D layout col = lane&15, row = (lane>>4)*4 + i
  const int orow0 = by * 256 + wr + (l >> 4) * 4;
  const int ocol0 = bx * BN + wc + (l & 15);
#pragma unroll
  for (int m = 0; m < 8; ++m)
#pragma unroll
    for (int n = 0; n < WN; ++n)
#pragma unroll
      for (int i = 0; i < 4; ++i) {
        const long r = orow0 + m * 16 + i;
        const long c = ocol0 + n * 16;
        const float v = acc[m][n][i] * alpha;
        if constexpr (EPI == 0) {
          ((bf16*)Cp)[z * sC + r * ldc + c] = (bf16)v;
        } else if constexpr (EPI == 2) {
          ((float*)Cp)[r * ldc + c] = v;
        }
      }
}

// ---------------- row softmax, in place, rows of 2048 bf16 ----------------
__global__ __launch_bounds__(256) void softmax_rows(bf16* __restrict__ P) {
  const long row = blockIdx.x;
  bf16* p = P + row * 2048;
  const int t = threadIdx.x;
  const int lane = t & 63;
  const int wave = t >> 6;

  u16x8 raw = *reinterpret_cast<const u16x8*>(p + t * 8);
  float v[8];
#pragma unroll
  for (int j = 0; j < 8; ++j) {
    uint32_t bits = ((uint32_t)raw[j]) << 16;
    v[j] = __builtin_bit_cast(float, bits);
  }
  float m = v[0];
#pragma unroll
  for (int j = 1; j < 8; ++j) m = fmaxf(m, v[j]);
#pragma unroll
  for (int off = 32; off > 0; off >>= 1) m = fmaxf(m, __shfl_xor(m, off, 64));
  __shared__ float redm[4];
  __shared__ float reds[4];
  if (lane == 0) redm[wave] = m;
  __syncthreads();
  m = fmaxf(fmaxf(redm[0], redm[1]), fmaxf(redm[2], redm[3]));

  float s = 0.f;
#pragma unroll
  for (int j = 0; j < 8; ++j) {
    v[j] = __expf(v[j] - m);
    s += v[j];
  }
#pragma unroll
  for (int off = 32; off > 0; off >>= 1) s += __shfl_xor(s, off, 64);
  if (lane == 0) reds[wave] = s;
  __syncthreads();
  s = reds[0] + reds[1] + reds[2] + reds[3];
  const float inv = 1.f / s;

  u16x8 o;
#pragma unroll
  for (int j = 0; j < 8; ++j) o[j] = __builtin_bit_cast(unsigned short, (bf16)(v[j] * inv));
  *reinterpret_cast<u16x8*>(p + t * 8) = o;
}

// ---------------- launch ----------------
extern "C" void kernel_launch(void* const* d_in, const int* in_sizes, int n_in,
                              void* d_out, int out_size, void* d_ws, size_t ws_size,
                              hipStream_t stream) {
  const float* q = (const float*)d_in[0];
  const float* wq = (const float*)d_in[1];
  const float* wk = (const float*)d_in[2];
  const float* wv = (const float*)d_in[3];
  const float* wo = (const float*)d_in[4];
  float* out = (float*)d_out;

  constexpr int B = 4, S = 2048, D = 1024;
  constexpr long SD = (long)S * D;  // 2,097,152
  constexpr long SS = (long)S * S;  // 4,194,304
  constexpr long DD = (long)D * D;  // 1,048,576

  bf16* wsb = (bf16*)d_ws;
  bf16* qb = wsb;             // B*SD
  bf16* W3 = qb + B * SD;     // 3*DD  (wq;wk;wv stacked rows)
  bf16* wob = W3 + 3 * DD;    // DD
  bf16* Qb = wob + DD;        // B*SD
  bf16* Kb = Qb + B * SD;     // B*SD
  bf16* Vt = Kb + B * SD;     // B*SD, layout [B][D][S]
  bf16* P = Vt + B * SD;      // B*SS
  bf16* X = P + B * SS;       // B*SD, layout [B][D][S] == bugged buffer

  cvt_all<<<3072, 256, 0, stream>>>(q, wq, wk, wv, wo, qb, W3, wob);

  // fused QKV: QK phase (WN=4, B = wq;wk) + V phase (B = wv, L2-hot A).
  // grid (8,32) = 256 blocks = 1/CU; 2D chunks 4x8.
  g256<6, 4><<<dim3(8, 32, 1), 512, 0, stream>>>(qb, W3, Qb, D, 1.f, 0, 0, 0, 0, 4, 8);
  // scores: per-z grid 8x8, chunks 4x2.
  g256<0, 4><<<dim3(8, 8, B), 512, 0, stream>>>(Qb, Kb, P, D, 0.125f, SD, SD, SS, S, 4, 2);
  softmax_rows<<<B * S, 256, 0, stream>>>(P);
  // PV as Xt = Vt @ P^T: per-z grid 16x4, chunks 4x2.
  g256<0, 2><<<dim3(16, 4, B), 512, 0, stream>>>(Vt, P, X, S, 1.f, SD, SS, SD, S, 4, 2);
  // out-proj: grid 8x32, chunks 4x8.
  g256<2, 2><<<dim3(8, 32, 1), 512, 0, stream>>>(X, wob, out, D, 1.f, 0, 0, 0, D, 4, 8);
}